// Round 21
// baseline (1678.745 us; speedup 1.0000x reference)
//
#include <hip/hip_runtime.h>

#define TT 32
#define NB 32   // nodes per GRU block (2 M-tiles per wave)

typedef __attribute__((ext_vector_type(8))) short short8;
typedef __attribute__((ext_vector_type(4))) float f32x4;

// ---------- helpers ----------
__device__ __host__ inline unsigned short f2bf(float f) {
    unsigned u = __float_as_uint(f);
    return (unsigned short)((u + 0x7FFFu + ((u >> 16) & 1u)) >> 16);
}
__device__ inline float bf2f(unsigned short h) {
    return __uint_as_float(((unsigned)h) << 16);
}

// ---------- weight prep ----------
__global__ void prep_w(const float* __restrict__ Wih_f, const float* __restrict__ Whh_f,
                       const float* __restrict__ Wih_b, const float* __restrict__ Whh_b,
                       const float* __restrict__ Wg,
                       unsigned short* __restrict__ Whi_f,
                       unsigned short* __restrict__ Whi_b,
                       unsigned short* __restrict__ Wghi, unsigned short* __restrict__ Wglo) {
    int i = blockIdx.x * 256 + threadIdx.x;
    if (i < 384 * 256) {
        int col = i / 256, k = i % 256;
        float ff = (k < 128) ? Wih_f[col * 128 + k] : Whh_f[col * 128 + (k - 128)];
        float fb = (k < 128) ? Wih_b[col * 128 + k] : Whh_b[col * 128 + (k - 128)];
        Whi_f[i] = f2bf(ff);
        Whi_b[i] = f2bf(fb);
    }
    if (i < 256 * 256) {
        float g = Wg[i];
        unsigned short h = f2bf(g);
        Wghi[i] = h; Wglo[i] = f2bf(g - bf2f(h));
    }
}

// ---------- emb bf16 plane prep (hi only) ----------
__global__ void prep_emb(const float* __restrict__ emb, unsigned short* __restrict__ ehi,
                         int n) {
    int i = blockIdx.x * 256 + threadIdx.x;
    if (i < n) ehi[i] = f2bf(emb[i]);
}

// ---------- fused biGRU: 1-pass bf16 A, waves_per_eu(4,4) -> 2 blocks/CU ----------
// R20 post-mortem: VALU-bound (59%), 1 block/CU at (2,2). R15's (4,4) failure
// needed 144+ VGPRs for 2-pass B; 1-pass B needs only 96 (measured total 120
// <= 128 cap) — retry. Two co-resident blocks overlap gate-VALU with MFMA/LDS.
// SUCCESS SIGNATURE: VGPR stays 96-128. FAILURE: VGPR ~64 + FETCH >1GB.
#define PIN(x) asm volatile("" : "+v"(x))
__global__ __launch_bounds__(512)
__attribute__((amdgpu_waves_per_eu(4, 4)))
void gru_kernel(const int* __restrict__ X,
                const unsigned short* __restrict__ ehi,
                const unsigned short* __restrict__ Whi_f,
                const unsigned short* __restrict__ Whi_b,
                const float* __restrict__ bih_f, const float* __restrict__ bhh_f,
                const float* __restrict__ bih_b, const float* __restrict__ bhh_b,
                float* __restrict__ q_out, float* __restrict__ qn_out, int N) {
    const int dir  = blockIdx.y;
    const int base = blockIdx.x * NB;
    const int tid  = threadIdx.x;
    const int lane = tid & 63;
    const int w    = tid >> 6;      // wave 0..7
    const int l15  = lane & 15;
    const int l4   = lane >> 4;     // 0..3

    const unsigned short* __restrict__ Whi = dir ? Whi_b : Whi_f;
    const float* __restrict__ bih = dir ? bih_b : bih_f;
    const float* __restrict__ bhh = dir ? bhh_b : bhh_f;

    // 2 buffers x 16KB (32 nodes x 256 k x bf16); buffer b at b*16384
    __shared__ __align__(16) char smem[32768];

    const int j = w * 16 + l15;        // owned output col (per gate)
    const float bR  = bih[j]       + bhh[j];
    const float bZ  = bih[j + 128] + bhh[j + 128];
    const float bXN = bih[j + 256];
    const float bHN = bhh[j + 256];

    // ---- load B fragments into registers (once) and PIN them ----
    short8 bh[3][8];
    #pragma unroll
    for (int g = 0; g < 3; g++)
        #pragma unroll
        for (int kc = 0; kc < 8; kc++) {
            int off = (g * 128 + j) * 256 + kc * 32 + l4 * 8;
            bh[g][kc] = *(const short8*)(Whi + off);
            PIN(bh[g][kc]);
        }

    // A-frag read bases: row = mt*16 + l15 (row&7 == l15&7 for both tiles)
    const int amask = (l15 & 7) << 4;
    int aob[2];
    #pragma unroll
    for (int mt = 0; mt < 2; mt++) aob[mt] = (mt * 16 + l15) * 512 + l4 * 16;

    // zero h-region of buffer 0 (rows 0..31, bytes 256..511)
    for (int i = tid; i < 2048; i += 512) {
        int row = i >> 6, d = i & 63;
        *(unsigned*)(smem + row * 512 + 256 + d * 4) = 0u;
    }

    // staging: thread -> (node snode, 8 k at sk); pure 16B copy
    const int snode = tid >> 4;          // 0..31
    const int sk    = (tid & 15) * 8;    // 0..120
    const int sb    = (snode * 512 + sk * 2) ^ ((snode & 7) << 4);
    int node_s = base + snode; if (node_s >= N) node_s = N - 1;
    const int* Xrow = X + (size_t)node_s * TT;
    auto teff = [&](int t) { return dir ? (TT - 1 - t) : t; };

    { // stage x(0) into buffer 0
        int idx0 = Xrow[teff(0)];
        *(uint4*)(smem + sb) = *(const uint4*)(ehi + (size_t)idx0 * 128 + sk);
    }
    int idxA = Xrow[teff(1)];    // index for x(1), prefetched

    float hprev[2][4] = {{0.f, 0.f, 0.f, 0.f}, {0.f, 0.f, 0.f, 0.f}};
    const int jd = j & ~1;       // even col of the (j, j^1) pair

    for (int t = 0; t < TT; t++) {
        __syncthreads();   // buf[cur] (x_t + h_t) fully written

        char* pA = smem + (t & 1) * 16384;        // current buffer
        char* pN = smem + ((t + 1) & 1) * 16384;  // next buffer

        // issue next-step staging loads (latency hidden under MFMA)
        uint4 uhi;
        if (t < TT - 1) {
            uhi = *(const uint4*)(ehi + (size_t)idxA * 128 + sk);
            if (t < TT - 2) idxA = Xrow[teff(t + 2)];
        }

        f32x4 aR[2], aZ[2], aNX[2], aNH[2];
        #pragma unroll
        for (int mt = 0; mt < 2; mt++) {
            aR[mt]  = (f32x4){0.f, 0.f, 0.f, 0.f};
            aZ[mt]  = (f32x4){0.f, 0.f, 0.f, 0.f};
            aNX[mt] = (f32x4){0.f, 0.f, 0.f, 0.f};
            aNH[mt] = (f32x4){0.f, 0.f, 0.f, 0.f};
        }
        #pragma unroll
        for (int kc = 0; kc < 8; kc++) {
            short8 bR8 = bh[0][kc], bZ8 = bh[1][kc], bN8 = bh[2][kc];
            #pragma unroll
            for (int mt = 0; mt < 2; mt++) {
                int ao = (aob[mt] + kc * 64) ^ amask;
                short8 ah = *(const short8*)(pA + ao);
                f32x4& an = (kc < 4) ? aNX[mt] : aNH[mt];
                aR[mt] = __builtin_amdgcn_mfma_f32_16x16x32_bf16(ah, bR8, aR[mt], 0, 0, 0);
                aZ[mt] = __builtin_amdgcn_mfma_f32_16x16x32_bf16(ah, bZ8, aZ[mt], 0, 0, 0);
                an     = __builtin_amdgcn_mfma_f32_16x16x32_bf16(ah, bN8, an, 0, 0, 0);
            }
        }

        // gates + h carry (fp32 in registers); bf16 h(t+1) -> NEXT buffer
        #pragma unroll
        for (int mt = 0; mt < 2; mt++)
            #pragma unroll
            for (int rr = 0; rr < 4; rr++) {
                int nl = mt * 16 + l4 * 4 + rr;    // local node (C/D row map)
                float r = 1.f / (1.f + __expf(-(aR[mt][rr] + bR)));
                float z = 1.f / (1.f + __expf(-(aZ[mt][rr] + bZ)));
                float p = aNX[mt][rr] + bXN + r * (aNH[mt][rr] + bHN);
                float n = 1.f - 2.f / (__expf(2.f * p) + 1.f);   // tanh
                float h = (1.f - z) * n + z * hprev[mt][rr];
                hprev[mt][rr] = h;
                unsigned short hh = f2bf(h);
                unsigned pk = (unsigned)hh;
                unsigned pp = __shfl_xor(pk, 1);
                if ((l15 & 1) == 0) {      // even lane writes the (j, j+1) pair
                    unsigned hiw = pk | (pp << 16);
                    int hb = (nl * 512 + 256 + 2 * jd) ^ ((nl & 7) << 4);
                    *(unsigned*)(pN + hb) = hiw;
                }
                int node = base + nl;
                if (node < N) {
                    q_out[((size_t)t * N + node) * 256 + dir * 128 + j] = h;
                    if (t == TT - 1)
                        qn_out[(size_t)node * 256 + dir * 128 + j] = h;
                }
            }
        // write staged x(t+1) into next buffer
        if (t < TT - 1) *(uint4*)(pN + sb) = uhi;
    }
}

// ---------- GAT: fused matmul + att-dots; writes Hm in bf16 ----------
__global__ __launch_bounds__(256)
void gat_matmul(const float* __restrict__ G,
                const unsigned short* __restrict__ Wghi, const unsigned short* __restrict__ Wglo,
                const float* __restrict__ att_src, const float* __restrict__ att_dst,
                unsigned short* __restrict__ HmBf,
                float* __restrict__ a_src, float* __restrict__ a_dst, int N) {
    const int base = blockIdx.x * 32;
    const int tid  = threadIdx.x;
    const int lane = tid & 63;
    const int w    = tid >> 6;      // wave 0..3
    const int l15  = lane & 15;
    const int l4   = lane >> 4;

    __shared__ __align__(16) char smem[32768];   // hi @0, lo @16384
    __shared__ float sred1[4][32], sred2[4][32];

    const int snode = tid >> 3;
    const int sk    = (tid & 7) * 32;
    const int smask = (snode & 7) << 4;
    int node_s = base + snode; if (node_s >= N) node_s = N - 1;
    const float* gr = G + (size_t)node_s * 256 + sk;
    #pragma unroll
    for (int c = 0; c < 4; c++) {
        float4 v0 = *(const float4*)(gr + c * 8);
        float4 v1 = *(const float4*)(gr + c * 8 + 4);
        unsigned short h0 = f2bf(v0.x), h1 = f2bf(v0.y), h2 = f2bf(v0.z), h3 = f2bf(v0.w);
        unsigned short h4 = f2bf(v1.x), h5 = f2bf(v1.y), h6 = f2bf(v1.z), h7 = f2bf(v1.w);
        uint4 hi = {(unsigned)h0 | ((unsigned)h1 << 16), (unsigned)h2 | ((unsigned)h3 << 16),
                    (unsigned)h4 | ((unsigned)h5 << 16), (unsigned)h6 | ((unsigned)h7 << 16)};
        uint4 lo = {(unsigned)f2bf(v0.x - bf2f(h0)) | ((unsigned)f2bf(v0.y - bf2f(h1)) << 16),
                    (unsigned)f2bf(v0.z - bf2f(h2)) | ((unsigned)f2bf(v0.w - bf2f(h3)) << 16),
                    (unsigned)f2bf(v1.x - bf2f(h4)) | ((unsigned)f2bf(v1.y - bf2f(h5)) << 16),
                    (unsigned)f2bf(v1.z - bf2f(h6)) | ((unsigned)f2bf(v1.w - bf2f(h7)) << 16)};
        int addr = (snode * 512 + (sk + c * 8) * 2) ^ smask;
        *(uint4*)(smem + addr) = hi;
        *(uint4*)(smem + 16384 + addr) = lo;
    }
    __syncthreads();

    int aob[2], amask[2];
    #pragma unroll
    for (int mt = 0; mt < 2; mt++) {
        int row = mt * 16 + l15;
        aob[mt]   = row * 512 + l4 * 16;
        amask[mt] = (row & 7) << 4;
    }
    int bb[4];
    #pragma unroll
    for (int th = 0; th < 4; th++)
        bb[th] = (w * 64 + th * 16 + l15) * 256 + l4 * 8;

    f32x4 acc[4][2];
    #pragma unroll
    for (int th = 0; th < 4; th++)
        #pragma unroll
        for (int mt = 0; mt < 2; mt++) acc[th][mt] = (f32x4){0.f, 0.f, 0.f, 0.f};

    #pragma unroll
    for (int kc = 0; kc < 8; kc++) {
        short8 ah[2], al[2];
        #pragma unroll
        for (int mt = 0; mt < 2; mt++) {
            int ao = (aob[mt] + kc * 64) ^ amask[mt];
            ah[mt] = *(const short8*)(smem + ao);
            al[mt] = *(const short8*)(smem + 16384 + ao);
        }
        #pragma unroll
        for (int th = 0; th < 4; th++) {
            int bo = bb[th] + kc * 32;
            short8 bhf = *(const short8*)(Wghi + bo);
            short8 blf = *(const short8*)(Wglo + bo);
            #pragma unroll
            for (int mt = 0; mt < 2; mt++) {
                acc[th][mt] = __builtin_amdgcn_mfma_f32_16x16x32_bf16(ah[mt], bhf, acc[th][mt], 0, 0, 0);
                acc[th][mt] = __builtin_amdgcn_mfma_f32_16x16x32_bf16(al[mt], bhf, acc[th][mt], 0, 0, 0);
                acc[th][mt] = __builtin_amdgcn_mfma_f32_16x16x32_bf16(ah[mt], blf, acc[th][mt], 0, 0, 0);
            }
        }
    }

    // ---- epilogue: bf16 H write + fused attention dots ----
    float s1p[2][4], s2p[2][4];
    #pragma unroll
    for (int mt = 0; mt < 2; mt++)
        #pragma unroll
        for (int rr = 0; rr < 4; rr++) { s1p[mt][rr] = 0.f; s2p[mt][rr] = 0.f; }
    #pragma unroll
    for (int th = 0; th < 4; th++) {
        int col = w * 64 + th * 16 + l15;
        float as = att_src[col], ad = att_dst[col];
        #pragma unroll
        for (int mt = 0; mt < 2; mt++)
            #pragma unroll
            for (int rr = 0; rr < 4; rr++) {
                float v = acc[th][mt][rr];
                s1p[mt][rr] += v * as;
                s2p[mt][rr] += v * ad;
                int node = base + mt * 16 + l4 * 4 + rr;
                if (node < N) HmBf[(size_t)node * 256 + col] = f2bf(v);
            }
    }
    #pragma unroll
    for (int o = 1; o < 16; o <<= 1)
        #pragma unroll
        for (int mt = 0; mt < 2; mt++)
            #pragma unroll
            for (int rr = 0; rr < 4; rr++) {
                s1p[mt][rr] += __shfl_xor(s1p[mt][rr], o);
                s2p[mt][rr] += __shfl_xor(s2p[mt][rr], o);
            }
    if (l15 == 0) {
        #pragma unroll
        for (int mt = 0; mt < 2; mt++)
            #pragma unroll
            for (int rr = 0; rr < 4; rr++) {
                int nl = mt * 16 + l4 * 4 + rr;
                sred1[w][nl] = s1p[mt][rr];
                sred2[w][nl] = s2p[mt][rr];
            }
    }
    __syncthreads();
    if (tid < 32) {
        int node = base + tid;
        if (node < N) {
            a_src[node] = sred1[0][tid] + sred1[1][tid] + sred1[2][tid] + sred1[3][tid];
            a_dst[node] = sred2[0][tid] + sred2[1][tid] + sred2[2][tid] + sred2[3][tid];
        }
    }
}

// ---------- GAT: fused CSR aggregate — exp inline, denom in-wave ----------
__global__ void gat_aggregate(const unsigned short* __restrict__ HmBf,
                              const int* __restrict__ off,
                              const int* __restrict__ srcs_sorted,
                              const float* __restrict__ a_src, const float* __restrict__ a_dst,
                              const float* __restrict__ bias,
                              float* __restrict__ Gout, int N) {
    int n = blockIdx.x * 4 + (threadIdx.x >> 6);
    int lane = threadIdx.x & 63;
    if (n >= N) return;
    int s0 = off[n], s1 = off[n + 1];
    float ad = a_dst[n];
    float4 acc = {0.f, 0.f, 0.f, 0.f};
    float den = 0.f;
    int e = s0;
    for (; e + 4 <= s1; e += 4) {
        int sA = srcs_sorted[e],     sB = srcs_sorted[e + 1];
        int sC = srcs_sorted[e + 2], sD = srcs_sorted[e + 3];
        float vA = a_src[sA] + ad, vB = a_src[sB] + ad;
        float vC = a_src[sC] + ad, vD = a_src[sD] + ad;
        vA = vA > 0.f ? vA : 0.2f * vA;  float wA = __expf(vA);
        vB = vB > 0.f ? vB : 0.2f * vB;  float wB = __expf(vB);
        vC = vC > 0.f ? vC : 0.2f * vC;  float wC = __expf(vC);
        vD = vD > 0.f ? vD : 0.2f * vD;  float wD = __expf(vD);
        den += (wA + wB) + (wC + wD);
        ushort4 a = *(const ushort4*)(HmBf + (size_t)sA * 256 + lane * 4);
        ushort4 b = *(const ushort4*)(HmBf + (size_t)sB * 256 + lane * 4);
        ushort4 c = *(const ushort4*)(HmBf + (size_t)sC * 256 + lane * 4);
        ushort4 d = *(const ushort4*)(HmBf + (size_t)sD * 256 + lane * 4);
        acc.x += bf2f(a.x) * wA + bf2f(b.x) * wB + bf2f(c.x) * wC + bf2f(d.x) * wD;
        acc.y += bf2f(a.y) * wA + bf2f(b.y) * wB + bf2f(c.y) * wC + bf2f(d.y) * wD;
        acc.z += bf2f(a.z) * wA + bf2f(b.z) * wB + bf2f(c.z) * wC + bf2f(d.z) * wD;
        acc.w += bf2f(a.w) * wA + bf2f(b.w) * wB + bf2f(c.w) * wC + bf2f(d.w) * wD;
    }
    for (; e < s1; e++) {
        int s = srcs_sorted[e];
        float v = a_src[s] + ad;
        v = v > 0.f ? v : 0.2f * v;
        float wgt = __expf(v);
        den += wgt;
        ushort4 a = *(const ushort4*)(HmBf + (size_t)s * 256 + lane * 4);
        acc.x += bf2f(a.x) * wgt; acc.y += bf2f(a.y) * wgt;
        acc.z += bf2f(a.z) * wgt; acc.w += bf2f(a.w) * wgt;
    }
    float inv = (s1 > s0) ? 1.f / den : 0.f;
    float4 b4 = *(const float4*)(bias + lane * 4);
    float4 o = {acc.x * inv + b4.x, acc.y * inv + b4.y,
                acc.z * inv + b4.z, acc.w * inv + b4.w};
    *(float4*)(Gout + (size_t)n * 256 + lane * 4) = o;
}

// ---------- CSR build ----------
__global__ void zero_int(int* p, int n) {
    int i = blockIdx.x * 256 + threadIdx.x;
    if (i < n) p[i] = 0;
}
__global__ void deg_count(const int* __restrict__ dst, int* __restrict__ deg, int E) {
    int i = blockIdx.x * 256 + threadIdx.x;
    if (i < E) atomicAdd(deg + dst[i], 1);
}
__global__ void scan_k(const int* __restrict__ deg, int* __restrict__ off,
                       int* __restrict__ cursor, int n) {
    __shared__ int buf[256];
    __shared__ int carry_s;
    int tid = threadIdx.x;
    if (tid == 0) carry_s = 0;
    __syncthreads();
    for (int base = 0; base < n; base += 256) {
        int v = (base + tid < n) ? deg[base + tid] : 0;
        buf[tid] = v;
        __syncthreads();
        int x = v;
        for (int s = 1; s < 256; s <<= 1) {
            int tv = (tid >= s) ? buf[tid - s] : 0;
            __syncthreads();
            x += tv; buf[tid] = x;
            __syncthreads();
        }
        int carry = carry_s;
        if (base + tid < n) { off[base + tid] = carry + x - v; cursor[base + tid] = carry + x - v; }
        __syncthreads();
        if (tid == 255) carry_s = carry + x;
        __syncthreads();
    }
    if (tid == 0) off[n] = carry_s;
}
__global__ void scatter_k(const int* __restrict__ src, const int* __restrict__ dst,
                          int* __restrict__ cursor, int* __restrict__ srcs_sorted, int E) {
    int i = blockIdx.x * 256 + threadIdx.x;
    if (i >= E) return;
    int p = atomicAdd(cursor + dst[i], 1);
    srcs_sorted[p] = src[i];
}

// ---------- launch ----------
extern "C" void kernel_launch(void* const* d_in, const int* in_sizes, int n_in,
                              void* d_out, int out_size, void* d_ws, size_t ws_size,
                              hipStream_t stream) {
    const int N = in_sizes[0] / TT;
    const int E = in_sizes[1] / 2;
    const int EMBN = in_sizes[2];          // V * 128

    const int* X         = (const int*)d_in[0];
    const int* ei        = (const int*)d_in[1];
    const int* srcp      = ei;
    const int* dstp      = ei + E;
    const float* emb     = (const float*)d_in[2];
    const float* Wih_f   = (const float*)d_in[3];
    const float* Whh_f   = (const float*)d_in[4];
    const float* bih_f   = (const float*)d_in[5];
    const float* bhh_f   = (const float*)d_in[6];
    const float* Wih_b   = (const float*)d_in[7];
    const float* Whh_b   = (const float*)d_in[8];
    const float* bih_b   = (const float*)d_in[9];
    const float* bhh_b   = (const float*)d_in[10];
    const float* Wg      = (const float*)d_in[11];
    const float* att_src = (const float*)d_in[12];
    const float* att_dst = (const float*)d_in[13];
    const float* bg      = (const float*)d_in[14];

    float* out     = (float*)d_out;
    float* g_final = out;
    float* qn      = out + (size_t)N * 256;
    float* q       = out + (size_t)2 * N * 256;

    // ws layout
    float* w = (float*)d_ws;
    unsigned short* Whi_f = (unsigned short*)w; w += 49152;  // 384*256 ushort
    unsigned short* Whi_b = (unsigned short*)w; w += 49152;
    unsigned short* Wghi  = (unsigned short*)w; w += 32768;  // 256*256 ushort
    unsigned short* Wglo  = (unsigned short*)w; w += 32768;
    unsigned short* ehi   = (unsigned short*)w; w += (EMBN + 1) / 2;
    float* bufA  = w; w += (size_t)N * 256;
    float* bufB  = w; w += (size_t)N * 256;
    unsigned short* HmBf = (unsigned short*)w; w += (size_t)N * 128;  // N*256 ushorts
    float* a_src = w; w += N;
    float* a_dst = w; w += N;
    int* iw = (int*)w;
    int* deg         = iw; iw += N;
    int* cursor      = iw; iw += N;
    int* off         = iw; iw += N + 1;
    int* srcs_sorted = iw; iw += E;

    // 1. weight + emb plane prep
    prep_w<<<384, 256, 0, stream>>>(Wih_f, Whh_f, Wih_b, Whh_b, Wg,
                                    Whi_f, Whi_b, Wghi, Wglo);
    prep_emb<<<(EMBN + 255) / 256, 256, 0, stream>>>(emb, ehi, EMBN);
    // 2. fused biGRU, writes q and q_n
    dim3 ggrid((N + NB - 1) / NB, 2);
    gru_kernel<<<ggrid, 512, 0, stream>>>(X, ehi, Whi_f, Whi_b,
                                          bih_f, bhh_f, bih_b, bhh_b, q, qn, N);
    // 3. CSR build (once, reused by all 4 layers)
    zero_int<<<(N + 255) / 256, 256, 0, stream>>>(deg, N);
    deg_count<<<(E + 255) / 256, 256, 0, stream>>>(dstp, deg, E);
    scan_k<<<1, 256, 0, stream>>>(deg, off, cursor, N);
    scatter_k<<<(E + 255) / 256, 256, 0, stream>>>(srcp, dstp, cursor, srcs_sorted, E);
    // 4. 4 GAT layers (shared weights); 2 kernels/layer
    const float* gin = qn;
    float* gouts[4] = {bufA, bufB, bufA, g_final};
    for (int l = 0; l < 4; l++) {
        gat_matmul<<<(N + 31) / 32, 256, 0, stream>>>(gin, Wghi, Wglo, att_src, att_dst,
                                                      HmBf, a_src, a_dst, N);
        gat_aggregate<<<(N + 3) / 4, 256, 0, stream>>>(HmBf, off, srcs_sorted,
                                                       a_src, a_dst, bg, gouts[l], N);
        gin = gouts[l];
    }
}

// Round 22
// 874.337 us; speedup vs baseline: 1.9200x; 1.9200x over previous
//
#include <hip/hip_runtime.h>

#define TT 32
#define NB 32   // nodes per GRU block (2 M-tiles per wave)

typedef __attribute__((ext_vector_type(8))) short short8;
typedef __attribute__((ext_vector_type(4))) float f32x4;

// ---------- helpers ----------
__device__ __host__ inline unsigned short f2bf(float f) {
    unsigned u = __float_as_uint(f);
    return (unsigned short)((u + 0x7FFFu + ((u >> 16) & 1u)) >> 16);
}
__device__ inline float bf2f(unsigned short h) {
    return __uint_as_float(((unsigned)h) << 16);
}

// ---------- weight prep ----------
__global__ void prep_w(const float* __restrict__ Wih_f, const float* __restrict__ Whh_f,
                       const float* __restrict__ Wih_b, const float* __restrict__ Whh_b,
                       const float* __restrict__ Wg,
                       unsigned short* __restrict__ Whi_f,
                       unsigned short* __restrict__ Whi_b,
                       unsigned short* __restrict__ Wghi, unsigned short* __restrict__ Wglo) {
    int i = blockIdx.x * 256 + threadIdx.x;
    if (i < 384 * 256) {
        int col = i / 256, k = i % 256;
        float ff = (k < 128) ? Wih_f[col * 128 + k] : Whh_f[col * 128 + (k - 128)];
        float fb = (k < 128) ? Wih_b[col * 128 + k] : Whh_b[col * 128 + (k - 128)];
        Whi_f[i] = f2bf(ff);
        Whi_b[i] = f2bf(fb);
    }
    if (i < 256 * 256) {
        float g = Wg[i];
        unsigned short h = f2bf(g);
        Wghi[i] = h; Wglo[i] = f2bf(g - bf2f(h));
    }
}

// ---------- emb bf16 plane prep (hi only) ----------
__global__ void prep_emb(const float* __restrict__ emb, unsigned short* __restrict__ ehi,
                         int n) {
    int i = blockIdx.x * 256 + threadIdx.x;
    if (i < n) ehi[i] = f2bf(emb[i]);
}

// ---------- fused biGRU: R20 config (567 us) + hoisted q addressing ----------
// R21 post-mortem: waves_per_eu(4,4) again collapsed VGPR to 64 and spilled B
// (3rd failure: R9/R15/R21 — allocator targets a sub-cap budget regardless of
// need). Occupancy lever DEAD; (2,2) is the only config where B survives.
// This round: revert + hoist per-element q_out/qn_out address arithmetic.
#define PIN(x) asm volatile("" : "+v"(x))
__global__ __launch_bounds__(512)
__attribute__((amdgpu_waves_per_eu(2, 2)))
void gru_kernel(const int* __restrict__ X,
                const unsigned short* __restrict__ ehi,
                const unsigned short* __restrict__ Whi_f,
                const unsigned short* __restrict__ Whi_b,
                const float* __restrict__ bih_f, const float* __restrict__ bhh_f,
                const float* __restrict__ bih_b, const float* __restrict__ bhh_b,
                float* __restrict__ q_out, float* __restrict__ qn_out, int N) {
    const int dir  = blockIdx.y;
    const int base = blockIdx.x * NB;
    const int tid  = threadIdx.x;
    const int lane = tid & 63;
    const int w    = tid >> 6;      // wave 0..7
    const int l15  = lane & 15;
    const int l4   = lane >> 4;     // 0..3

    const unsigned short* __restrict__ Whi = dir ? Whi_b : Whi_f;
    const float* __restrict__ bih = dir ? bih_b : bih_f;
    const float* __restrict__ bhh = dir ? bhh_b : bhh_f;

    // 2 buffers x 16KB (32 nodes x 256 k x bf16); buffer b at b*16384
    __shared__ __align__(16) char smem[32768];

    const int j = w * 16 + l15;        // owned output col (per gate)
    const float bR  = bih[j]       + bhh[j];
    const float bZ  = bih[j + 128] + bhh[j + 128];
    const float bXN = bih[j + 256];
    const float bHN = bhh[j + 256];

    // ---- load B fragments into registers (once) and PIN them ----
    short8 bh[3][8];
    #pragma unroll
    for (int g = 0; g < 3; g++)
        #pragma unroll
        for (int kc = 0; kc < 8; kc++) {
            int off = (g * 128 + j) * 256 + kc * 32 + l4 * 8;
            bh[g][kc] = *(const short8*)(Whi + off);
            PIN(bh[g][kc]);
        }

    // A-frag read bases: row = mt*16 + l15 (row&7 == l15&7 for both tiles)
    const int amask = (l15 & 7) << 4;
    int aob[2];
    #pragma unroll
    for (int mt = 0; mt < 2; mt++) aob[mt] = (mt * 16 + l15) * 512 + l4 * 16;

    // zero h-region of buffer 0 (rows 0..31, bytes 256..511)
    for (int i = tid; i < 2048; i += 512) {
        int row = i >> 6, d = i & 63;
        *(unsigned*)(smem + row * 512 + 256 + d * 4) = 0u;
    }

    // staging: thread -> (node snode, 8 k at sk); pure 16B copy
    const int snode = tid >> 4;          // 0..31
    const int sk    = (tid & 15) * 8;    // 0..120
    const int sb    = (snode * 512 + sk * 2) ^ ((snode & 7) << 4);
    int node_s = base + snode; if (node_s >= N) node_s = N - 1;
    const int* Xrow = X + (size_t)node_s * TT;
    auto teff = [&](int t) { return dir ? (TT - 1 - t) : t; };

    { // stage x(0) into buffer 0
        int idx0 = Xrow[teff(0)];
        *(uint4*)(smem + sb) = *(const uint4*)(ehi + (size_t)idx0 * 128 + sk);
    }
    int idxA = Xrow[teff(1)];    // index for x(1), prefetched

    float hprev[2][4] = {{0.f, 0.f, 0.f, 0.f}, {0.f, 0.f, 0.f, 0.f}};
    const int jd = j & ~1;       // even col of the (j, j^1) pair

    // hoisted output bases: element addr = qt + nl*256 (nl const per unroll)
    const int nl0 = l4 * 4;                      // first local node this lane owns
    float* qt  = q_out + (size_t)(base + nl0) * 256 + dir * 128 + j;   // t=0
    float* qnb = qn_out + (size_t)(base + nl0) * 256 + dir * 128 + j;
    const size_t qstep = (size_t)N * 256;        // per-t increment
    const int nvalid = N - base;                 // nl < nvalid => node in range

    for (int t = 0; t < TT; t++) {
        __syncthreads();   // buf[cur] (x_t + h_t) fully written

        char* pA = smem + (t & 1) * 16384;        // current buffer
        char* pN = smem + ((t + 1) & 1) * 16384;  // next buffer

        // issue next-step staging loads (latency hidden under MFMA)
        uint4 uhi;
        if (t < TT - 1) {
            uhi = *(const uint4*)(ehi + (size_t)idxA * 128 + sk);
            if (t < TT - 2) idxA = Xrow[teff(t + 2)];
        }

        f32x4 aR[2], aZ[2], aNX[2], aNH[2];
        #pragma unroll
        for (int mt = 0; mt < 2; mt++) {
            aR[mt]  = (f32x4){0.f, 0.f, 0.f, 0.f};
            aZ[mt]  = (f32x4){0.f, 0.f, 0.f, 0.f};
            aNX[mt] = (f32x4){0.f, 0.f, 0.f, 0.f};
            aNH[mt] = (f32x4){0.f, 0.f, 0.f, 0.f};
        }
        #pragma unroll
        for (int kc = 0; kc < 8; kc++) {
            short8 bR8 = bh[0][kc], bZ8 = bh[1][kc], bN8 = bh[2][kc];
            #pragma unroll
            for (int mt = 0; mt < 2; mt++) {
                int ao = (aob[mt] + kc * 64) ^ amask;
                short8 ah = *(const short8*)(pA + ao);
                f32x4& an = (kc < 4) ? aNX[mt] : aNH[mt];
                aR[mt] = __builtin_amdgcn_mfma_f32_16x16x32_bf16(ah, bR8, aR[mt], 0, 0, 0);
                aZ[mt] = __builtin_amdgcn_mfma_f32_16x16x32_bf16(ah, bZ8, aZ[mt], 0, 0, 0);
                an     = __builtin_amdgcn_mfma_f32_16x16x32_bf16(ah, bN8, an, 0, 0, 0);
            }
        }

        // gates + h carry (fp32 in registers); bf16 h(t+1) -> NEXT buffer
        #pragma unroll
        for (int mt = 0; mt < 2; mt++)
            #pragma unroll
            for (int rr = 0; rr < 4; rr++) {
                int nl = mt * 16 + nl0 + rr;       // local node (C/D row map)
                float r = 1.f / (1.f + __expf(-(aR[mt][rr] + bR)));
                float z = 1.f / (1.f + __expf(-(aZ[mt][rr] + bZ)));
                float p = aNX[mt][rr] + bXN + r * (aNH[mt][rr] + bHN);
                float n = 1.f - 2.f / (__expf(2.f * p) + 1.f);   // tanh
                float h = (1.f - z) * n + z * hprev[mt][rr];
                hprev[mt][rr] = h;
                unsigned short hh = f2bf(h);
                unsigned pk = (unsigned)hh;
                unsigned pp = __shfl_xor(pk, 1);
                if ((l15 & 1) == 0) {      // even lane writes the (j, j+1) pair
                    unsigned hiw = pk | (pp << 16);
                    int hb = (nl * 512 + 256 + 2 * jd) ^ ((nl & 7) << 4);
                    *(unsigned*)(pN + hb) = hiw;
                }
                if (nl < nvalid) {
                    qt[(mt * 16 + rr) * 256] = h;
                    if (t == TT - 1) qnb[(mt * 16 + rr) * 256] = h;
                }
            }
        // write staged x(t+1) into next buffer
        if (t < TT - 1) *(uint4*)(pN + sb) = uhi;
        qt += qstep;
    }
}

// ---------- GAT: fused matmul + att-dots; writes Hm in bf16 ----------
__global__ __launch_bounds__(256)
void gat_matmul(const float* __restrict__ G,
                const unsigned short* __restrict__ Wghi, const unsigned short* __restrict__ Wglo,
                const float* __restrict__ att_src, const float* __restrict__ att_dst,
                unsigned short* __restrict__ HmBf,
                float* __restrict__ a_src, float* __restrict__ a_dst, int N) {
    const int base = blockIdx.x * 32;
    const int tid  = threadIdx.x;
    const int lane = tid & 63;
    const int w    = tid >> 6;      // wave 0..3
    const int l15  = lane & 15;
    const int l4   = lane >> 4;

    __shared__ __align__(16) char smem[32768];   // hi @0, lo @16384
    __shared__ float sred1[4][32], sred2[4][32];

    const int snode = tid >> 3;
    const int sk    = (tid & 7) * 32;
    const int smask = (snode & 7) << 4;
    int node_s = base + snode; if (node_s >= N) node_s = N - 1;
    const float* gr = G + (size_t)node_s * 256 + sk;
    #pragma unroll
    for (int c = 0; c < 4; c++) {
        float4 v0 = *(const float4*)(gr + c * 8);
        float4 v1 = *(const float4*)(gr + c * 8 + 4);
        unsigned short h0 = f2bf(v0.x), h1 = f2bf(v0.y), h2 = f2bf(v0.z), h3 = f2bf(v0.w);
        unsigned short h4 = f2bf(v1.x), h5 = f2bf(v1.y), h6 = f2bf(v1.z), h7 = f2bf(v1.w);
        uint4 hi = {(unsigned)h0 | ((unsigned)h1 << 16), (unsigned)h2 | ((unsigned)h3 << 16),
                    (unsigned)h4 | ((unsigned)h5 << 16), (unsigned)h6 | ((unsigned)h7 << 16)};
        uint4 lo = {(unsigned)f2bf(v0.x - bf2f(h0)) | ((unsigned)f2bf(v0.y - bf2f(h1)) << 16),
                    (unsigned)f2bf(v0.z - bf2f(h2)) | ((unsigned)f2bf(v0.w - bf2f(h3)) << 16),
                    (unsigned)f2bf(v1.x - bf2f(h4)) | ((unsigned)f2bf(v1.y - bf2f(h5)) << 16),
                    (unsigned)f2bf(v1.z - bf2f(h6)) | ((unsigned)f2bf(v1.w - bf2f(h7)) << 16)};
        int addr = (snode * 512 + (sk + c * 8) * 2) ^ smask;
        *(uint4*)(smem + addr) = hi;
        *(uint4*)(smem + 16384 + addr) = lo;
    }
    __syncthreads();

    int aob[2], amask[2];
    #pragma unroll
    for (int mt = 0; mt < 2; mt++) {
        int row = mt * 16 + l15;
        aob[mt]   = row * 512 + l4 * 16;
        amask[mt] = (row & 7) << 4;
    }
    int bb[4];
    #pragma unroll
    for (int th = 0; th < 4; th++)
        bb[th] = (w * 64 + th * 16 + l15) * 256 + l4 * 8;

    f32x4 acc[4][2];
    #pragma unroll
    for (int th = 0; th < 4; th++)
        #pragma unroll
        for (int mt = 0; mt < 2; mt++) acc[th][mt] = (f32x4){0.f, 0.f, 0.f, 0.f};

    #pragma unroll
    for (int kc = 0; kc < 8; kc++) {
        short8 ah[2], al[2];
        #pragma unroll
        for (int mt = 0; mt < 2; mt++) {
            int ao = (aob[mt] + kc * 64) ^ amask[mt];
            ah[mt] = *(const short8*)(smem + ao);
            al[mt] = *(const short8*)(smem + 16384 + ao);
        }
        #pragma unroll
        for (int th = 0; th < 4; th++) {
            int bo = bb[th] + kc * 32;
            short8 bhf = *(const short8*)(Wghi + bo);
            short8 blf = *(const short8*)(Wglo + bo);
            #pragma unroll
            for (int mt = 0; mt < 2; mt++) {
                acc[th][mt] = __builtin_amdgcn_mfma_f32_16x16x32_bf16(ah[mt], bhf, acc[th][mt], 0, 0, 0);
                acc[th][mt] = __builtin_amdgcn_mfma_f32_16x16x32_bf16(al[mt], bhf, acc[th][mt], 0, 0, 0);
                acc[th][mt] = __builtin_amdgcn_mfma_f32_16x16x32_bf16(ah[mt], blf, acc[th][mt], 0, 0, 0);
            }
        }
    }

    // ---- epilogue: bf16 H write + fused attention dots ----
    float s1p[2][4], s2p[2][4];
    #pragma unroll
    for (int mt = 0; mt < 2; mt++)
        #pragma unroll
        for (int rr = 0; rr < 4; rr++) { s1p[mt][rr] = 0.f; s2p[mt][rr] = 0.f; }
    #pragma unroll
    for (int th = 0; th < 4; th++) {
        int col = w * 64 + th * 16 + l15;
        float as = att_src[col], ad = att_dst[col];
        #pragma unroll
        for (int mt = 0; mt < 2; mt++)
            #pragma unroll
            for (int rr = 0; rr < 4; rr++) {
                float v = acc[th][mt][rr];
                s1p[mt][rr] += v * as;
                s2p[mt][rr] += v * ad;
                int node = base + mt * 16 + l4 * 4 + rr;
                if (node < N) HmBf[(size_t)node * 256 + col] = f2bf(v);
            }
    }
    #pragma unroll
    for (int o = 1; o < 16; o <<= 1)
        #pragma unroll
        for (int mt = 0; mt < 2; mt++)
            #pragma unroll
            for (int rr = 0; rr < 4; rr++) {
                s1p[mt][rr] += __shfl_xor(s1p[mt][rr], o);
                s2p[mt][rr] += __shfl_xor(s2p[mt][rr], o);
            }
    if (l15 == 0) {
        #pragma unroll
        for (int mt = 0; mt < 2; mt++)
            #pragma unroll
            for (int rr = 0; rr < 4; rr++) {
                int nl = mt * 16 + l4 * 4 + rr;
                sred1[w][nl] = s1p[mt][rr];
                sred2[w][nl] = s2p[mt][rr];
            }
    }
    __syncthreads();
    if (tid < 32) {
        int node = base + tid;
        if (node < N) {
            a_src[node] = sred1[0][tid] + sred1[1][tid] + sred1[2][tid] + sred1[3][tid];
            a_dst[node] = sred2[0][tid] + sred2[1][tid] + sred2[2][tid] + sred2[3][tid];
        }
    }
}

// ---------- GAT: fused CSR aggregate — exp inline, denom in-wave ----------
__global__ void gat_aggregate(const unsigned short* __restrict__ HmBf,
                              const int* __restrict__ off,
                              const int* __restrict__ srcs_sorted,
                              const float* __restrict__ a_src, const float* __restrict__ a_dst,
                              const float* __restrict__ bias,
                              float* __restrict__ Gout, int N) {
    int n = blockIdx.x * 4 + (threadIdx.x >> 6);
    int lane = threadIdx.x & 63;
    if (n >= N) return;
    int s0 = off[n], s1 = off[n + 1];
    float ad = a_dst[n];
    float4 acc = {0.f, 0.f, 0.f, 0.f};
    float den = 0.f;
    int e = s0;
    for (; e + 4 <= s1; e += 4) {
        int sA = srcs_sorted[e],     sB = srcs_sorted[e + 1];
        int sC = srcs_sorted[e + 2], sD = srcs_sorted[e + 3];
        float vA = a_src[sA] + ad, vB = a_src[sB] + ad;
        float vC = a_src[sC] + ad, vD = a_src[sD] + ad;
        vA = vA > 0.f ? vA : 0.2f * vA;  float wA = __expf(vA);
        vB = vB > 0.f ? vB : 0.2f * vB;  float wB = __expf(vB);
        vC = vC > 0.f ? vC : 0.2f * vC;  float wC = __expf(vC);
        vD = vD > 0.f ? vD : 0.2f * vD;  float wD = __expf(vD);
        den += (wA + wB) + (wC + wD);
        ushort4 a = *(const ushort4*)(HmBf + (size_t)sA * 256 + lane * 4);
        ushort4 b = *(const ushort4*)(HmBf + (size_t)sB * 256 + lane * 4);
        ushort4 c = *(const ushort4*)(HmBf + (size_t)sC * 256 + lane * 4);
        ushort4 d = *(const ushort4*)(HmBf + (size_t)sD * 256 + lane * 4);
        acc.x += bf2f(a.x) * wA + bf2f(b.x) * wB + bf2f(c.x) * wC + bf2f(d.x) * wD;
        acc.y += bf2f(a.y) * wA + bf2f(b.y) * wB + bf2f(c.y) * wC + bf2f(d.y) * wD;
        acc.z += bf2f(a.z) * wA + bf2f(b.z) * wB + bf2f(c.z) * wC + bf2f(d.z) * wD;
        acc.w += bf2f(a.w) * wA + bf2f(b.w) * wB + bf2f(c.w) * wC + bf2f(d.w) * wD;
    }
    for (; e < s1; e++) {
        int s = srcs_sorted[e];
        float v = a_src[s] + ad;
        v = v > 0.f ? v : 0.2f * v;
        float wgt = __expf(v);
        den += wgt;
        ushort4 a = *(const ushort4*)(HmBf + (size_t)s * 256 + lane * 4);
        acc.x += bf2f(a.x) * wgt; acc.y += bf2f(a.y) * wgt;
        acc.z += bf2f(a.z) * wgt; acc.w += bf2f(a.w) * wgt;
    }
    float inv = (s1 > s0) ? 1.f / den : 0.f;
    float4 b4 = *(const float4*)(bias + lane * 4);
    float4 o = {acc.x * inv + b4.x, acc.y * inv + b4.y,
                acc.z * inv + b4.z, acc.w * inv + b4.w};
    *(float4*)(Gout + (size_t)n * 256 + lane * 4) = o;
}

// ---------- CSR build ----------
__global__ void zero_int(int* p, int n) {
    int i = blockIdx.x * 256 + threadIdx.x;
    if (i < n) p[i] = 0;
}
__global__ void deg_count(const int* __restrict__ dst, int* __restrict__ deg, int E) {
    int i = blockIdx.x * 256 + threadIdx.x;
    if (i < E) atomicAdd(deg + dst[i], 1);
}
__global__ void scan_k(const int* __restrict__ deg, int* __restrict__ off,
                       int* __restrict__ cursor, int n) {
    __shared__ int buf[256];
    __shared__ int carry_s;
    int tid = threadIdx.x;
    if (tid == 0) carry_s = 0;
    __syncthreads();
    for (int base = 0; base < n; base += 256) {
        int v = (base + tid < n) ? deg[base + tid] : 0;
        buf[tid] = v;
        __syncthreads();
        int x = v;
        for (int s = 1; s < 256; s <<= 1) {
            int tv = (tid >= s) ? buf[tid - s] : 0;
            __syncthreads();
            x += tv; buf[tid] = x;
            __syncthreads();
        }
        int carry = carry_s;
        if (base + tid < n) { off[base + tid] = carry + x - v; cursor[base + tid] = carry + x - v; }
        __syncthreads();
        if (tid == 255) carry_s = carry + x;
        __syncthreads();
    }
    if (tid == 0) off[n] = carry_s;
}
__global__ void scatter_k(const int* __restrict__ src, const int* __restrict__ dst,
                          int* __restrict__ cursor, int* __restrict__ srcs_sorted, int E) {
    int i = blockIdx.x * 256 + threadIdx.x;
    if (i >= E) return;
    int p = atomicAdd(cursor + dst[i], 1);
    srcs_sorted[p] = src[i];
}

// ---------- launch ----------
extern "C" void kernel_launch(void* const* d_in, const int* in_sizes, int n_in,
                              void* d_out, int out_size, void* d_ws, size_t ws_size,
                              hipStream_t stream) {
    const int N = in_sizes[0] / TT;
    const int E = in_sizes[1] / 2;
    const int EMBN = in_sizes[2];          // V * 128

    const int* X         = (const int*)d_in[0];
    const int* ei        = (const int*)d_in[1];
    const int* srcp      = ei;
    const int* dstp      = ei + E;
    const float* emb     = (const float*)d_in[2];
    const float* Wih_f   = (const float*)d_in[3];
    const float* Whh_f   = (const float*)d_in[4];
    const float* bih_f   = (const float*)d_in[5];
    const float* bhh_f   = (const float*)d_in[6];
    const float* Wih_b   = (const float*)d_in[7];
    const float* Whh_b   = (const float*)d_in[8];
    const float* bih_b   = (const float*)d_in[9];
    const float* bhh_b   = (const float*)d_in[10];
    const float* Wg      = (const float*)d_in[11];
    const float* att_src = (const float*)d_in[12];
    const float* att_dst = (const float*)d_in[13];
    const float* bg      = (const float*)d_in[14];

    float* out     = (float*)d_out;
    float* g_final = out;
    float* qn      = out + (size_t)N * 256;
    float* q       = out + (size_t)2 * N * 256;

    // ws layout
    float* w = (float*)d_ws;
    unsigned short* Whi_f = (unsigned short*)w; w += 49152;  // 384*256 ushort
    unsigned short* Whi_b = (unsigned short*)w; w += 49152;
    unsigned short* Wghi  = (unsigned short*)w; w += 32768;  // 256*256 ushort
    unsigned short* Wglo  = (unsigned short*)w; w += 32768;
    unsigned short* ehi   = (unsigned short*)w; w += (EMBN + 1) / 2;
    float* bufA  = w; w += (size_t)N * 256;
    float* bufB  = w; w += (size_t)N * 256;
    unsigned short* HmBf = (unsigned short*)w; w += (size_t)N * 128;  // N*256 ushorts
    float* a_src = w; w += N;
    float* a_dst = w; w += N;
    int* iw = (int*)w;
    int* deg         = iw; iw += N;
    int* cursor      = iw; iw += N;
    int* off         = iw; iw += N + 1;
    int* srcs_sorted = iw; iw += E;

    // 1. weight + emb plane prep
    prep_w<<<384, 256, 0, stream>>>(Wih_f, Whh_f, Wih_b, Whh_b, Wg,
                                    Whi_f, Whi_b, Wghi, Wglo);
    prep_emb<<<(EMBN + 255) / 256, 256, 0, stream>>>(emb, ehi, EMBN);
    // 2. fused biGRU, writes q and q_n
    dim3 ggrid((N + NB - 1) / NB, 2);
    gru_kernel<<<ggrid, 512, 0, stream>>>(X, ehi, Whi_f, Whi_b,
                                          bih_f, bhh_f, bih_b, bhh_b, q, qn, N);
    // 3. CSR build (once, reused by all 4 layers)
    zero_int<<<(N + 255) / 256, 256, 0, stream>>>(deg, N);
    deg_count<<<(E + 255) / 256, 256, 0, stream>>>(dstp, deg, E);
    scan_k<<<1, 256, 0, stream>>>(deg, off, cursor, N);
    scatter_k<<<(E + 255) / 256, 256, 0, stream>>>(srcp, dstp, cursor, srcs_sorted, E);
    // 4. 4 GAT layers (shared weights); 2 kernels/layer
    const float* gin = qn;
    float* gouts[4] = {bufA, bufB, bufA, g_final};
    for (int l = 0; l < 4; l++) {
        gat_matmul<<<(N + 31) / 32, 256, 0, stream>>>(gin, Wghi, Wglo, att_src, att_dst,
                                                      HmBf, a_src, a_dst, N);
        gat_aggregate<<<(N + 3) / 4, 256, 0, stream>>>(HmBf, off, srcs_sorted,
                                                       a_src, a_dst, bg, gouts[l], N);
        gin = gouts[l];
    }
}

// Round 23
// 683.884 us; speedup vs baseline: 2.4547x; 1.2785x over previous
//
#include <hip/hip_runtime.h>

#define TT 32
#define NB 32   // nodes per GRU block (2 M-tiles per wave)

typedef __attribute__((ext_vector_type(8))) short short8;
typedef __attribute__((ext_vector_type(4))) float f32x4;

#define LOG2E  1.4426950408889634f
#define LOG2E2 2.8853900817779268f

// ---------- helpers ----------
__device__ __host__ inline unsigned short f2bf(float f) {
    unsigned u = __float_as_uint(f);
    return (unsigned short)((u + 0x7FFFu + ((u >> 16) & 1u)) >> 16);
}
__device__ inline float bf2f(unsigned short h) {
    return __uint_as_float(((unsigned)h) << 16);
}

// ---------- weight prep ----------
// GRU W planes [384 col][256 k] bf16, PRE-SCALED: r,z cols (0..255) by
// -log2e (sigmoid via exp2, sign folded); n cols (256..383) by +2*log2e
// (tanh via exp2(2p)). Scaling precedes bf16 quantization -> same rel error.
__global__ void prep_w(const float* __restrict__ Wih_f, const float* __restrict__ Whh_f,
                       const float* __restrict__ Wih_b, const float* __restrict__ Whh_b,
                       const float* __restrict__ Wg,
                       unsigned short* __restrict__ Whi_f,
                       unsigned short* __restrict__ Whi_b,
                       unsigned short* __restrict__ Wghi, unsigned short* __restrict__ Wglo) {
    int i = blockIdx.x * 256 + threadIdx.x;
    if (i < 384 * 256) {
        int col = i / 256, k = i % 256;
        float s = (col < 256) ? -LOG2E : LOG2E2;
        float ff = (k < 128) ? Wih_f[col * 128 + k] : Whh_f[col * 128 + (k - 128)];
        float fb = (k < 128) ? Wih_b[col * 128 + k] : Whh_b[col * 128 + (k - 128)];
        Whi_f[i] = f2bf(s * ff);
        Whi_b[i] = f2bf(s * fb);
    }
    if (i < 256 * 256) {
        float g = Wg[i];
        unsigned short h = f2bf(g);
        Wghi[i] = h; Wglo[i] = f2bf(g - bf2f(h));
    }
}

// ---------- emb bf16 plane prep (hi only) ----------
__global__ void prep_emb(const float* __restrict__ emb, unsigned short* __restrict__ ehi,
                         int n) {
    int i = blockIdx.x * 256 + threadIdx.x;
    if (i < n) ehi[i] = f2bf(emb[i]);
}

// ---------- fused biGRU: R20/R22 structure + exp2/rcp/cvt_pk gate math ----------
// R22 post-mortem: VALU-issue-bound (57.5%) at the pinned 1 block/CU.
// This round shrinks the gate epilogue: (1) log2e folded into W/biases ->
// v_exp_f32 used directly as exp2; (2) raw v_rcp_f32 (no Newton refine);
// (3) v_cvt_pk_bf16_f32 + direct ds_write_b16 h writeback (2-way alias free).
#define PIN(x) asm volatile("" : "+v"(x))
#define EXP2(d, s) asm("v_exp_f32 %0, %1" : "=v"(d) : "v"(s))
__global__ __launch_bounds__(512)
__attribute__((amdgpu_waves_per_eu(2, 2)))
void gru_kernel(const int* __restrict__ X,
                const unsigned short* __restrict__ ehi,
                const unsigned short* __restrict__ Whi_f,
                const unsigned short* __restrict__ Whi_b,
                const float* __restrict__ bih_f, const float* __restrict__ bhh_f,
                const float* __restrict__ bih_b, const float* __restrict__ bhh_b,
                float* __restrict__ q_out, float* __restrict__ qn_out, int N) {
    const int dir  = blockIdx.y;
    const int base = blockIdx.x * NB;
    const int tid  = threadIdx.x;
    const int lane = tid & 63;
    const int w    = tid >> 6;      // wave 0..7
    const int l15  = lane & 15;
    const int l4   = lane >> 4;     // 0..3

    const unsigned short* __restrict__ Whi = dir ? Whi_b : Whi_f;
    const float* __restrict__ bih = dir ? bih_b : bih_f;
    const float* __restrict__ bhh = dir ? bhh_b : bhh_f;

    // 2 buffers x 16KB (32 nodes x 256 k x bf16); buffer b at b*16384
    __shared__ __align__(16) char smem[32768];

    const int j = w * 16 + l15;        // owned output col (per gate)
    // biases pre-scaled to match the weight scaling
    const float bR  = -LOG2E * (bih[j] + bhh[j]);
    const float bZ  = -LOG2E * (bih[j + 128] + bhh[j + 128]);
    const float bXN = LOG2E2 * bih[j + 256];
    const float bHN = LOG2E2 * bhh[j + 256];

    // ---- load B fragments into registers (once) and PIN them ----
    short8 bh[3][8];
    #pragma unroll
    for (int g = 0; g < 3; g++)
        #pragma unroll
        for (int kc = 0; kc < 8; kc++) {
            int off = (g * 128 + j) * 256 + kc * 32 + l4 * 8;
            bh[g][kc] = *(const short8*)(Whi + off);
            PIN(bh[g][kc]);
        }

    // A-frag read bases: row = mt*16 + l15 (row&7 == l15&7 for both tiles)
    const int amask = (l15 & 7) << 4;
    int aob[2];
    #pragma unroll
    for (int mt = 0; mt < 2; mt++) aob[mt] = (mt * 16 + l15) * 512 + l4 * 16;

    // zero h-region of buffer 0 (rows 0..31, bytes 256..511)
    for (int i = tid; i < 2048; i += 512) {
        int row = i >> 6, d = i & 63;
        *(unsigned*)(smem + row * 512 + 256 + d * 4) = 0u;
    }

    // staging: thread -> (node snode, 8 k at sk); pure 16B copy
    const int snode = tid >> 4;          // 0..31
    const int sk    = (tid & 15) * 8;    // 0..120
    const int sb    = (snode * 512 + sk * 2) ^ ((snode & 7) << 4);
    int node_s = base + snode; if (node_s >= N) node_s = N - 1;
    const int* Xrow = X + (size_t)node_s * TT;
    auto teff = [&](int t) { return dir ? (TT - 1 - t) : t; };

    { // stage x(0) into buffer 0
        int idx0 = Xrow[teff(0)];
        *(uint4*)(smem + sb) = *(const uint4*)(ehi + (size_t)idx0 * 128 + sk);
    }
    int idxA = Xrow[teff(1)];    // index for x(1), prefetched

    float hprev[2][4] = {{0.f, 0.f, 0.f, 0.f}, {0.f, 0.f, 0.f, 0.f}};

    // hoisted output bases: element addr = qt + (mt*16+rr)*256
    const int nl0 = l4 * 4;
    float* qt  = q_out + (size_t)(base + nl0) * 256 + dir * 128 + j;   // t=0
    float* qnb = qn_out + (size_t)(base + nl0) * 256 + dir * 128 + j;
    const size_t qstep = (size_t)N * 256;
    const int nvalid = N - base;

    for (int t = 0; t < TT; t++) {
        __syncthreads();   // buf[cur] (x_t + h_t) fully written

        char* pA = smem + (t & 1) * 16384;        // current buffer
        char* pN = smem + ((t + 1) & 1) * 16384;  // next buffer

        // issue next-step staging loads (latency hidden under MFMA)
        uint4 uhi;
        if (t < TT - 1) {
            uhi = *(const uint4*)(ehi + (size_t)idxA * 128 + sk);
            if (t < TT - 2) idxA = Xrow[teff(t + 2)];
        }

        f32x4 aR[2], aZ[2], aNX[2], aNH[2];
        #pragma unroll
        for (int mt = 0; mt < 2; mt++) {
            aR[mt]  = (f32x4){0.f, 0.f, 0.f, 0.f};
            aZ[mt]  = (f32x4){0.f, 0.f, 0.f, 0.f};
            aNX[mt] = (f32x4){0.f, 0.f, 0.f, 0.f};
            aNH[mt] = (f32x4){0.f, 0.f, 0.f, 0.f};
        }
        #pragma unroll
        for (int kc = 0; kc < 8; kc++) {
            short8 bR8 = bh[0][kc], bZ8 = bh[1][kc], bN8 = bh[2][kc];
            #pragma unroll
            for (int mt = 0; mt < 2; mt++) {
                int ao = (aob[mt] + kc * 64) ^ amask;
                short8 ah = *(const short8*)(pA + ao);
                f32x4& an = (kc < 4) ? aNX[mt] : aNH[mt];
                aR[mt] = __builtin_amdgcn_mfma_f32_16x16x32_bf16(ah, bR8, aR[mt], 0, 0, 0);
                aZ[mt] = __builtin_amdgcn_mfma_f32_16x16x32_bf16(ah, bZ8, aZ[mt], 0, 0, 0);
                an     = __builtin_amdgcn_mfma_f32_16x16x32_bf16(ah, bN8, an, 0, 0, 0);
            }
        }

        // gates (exp2 form) + fp32 h carry; bf16 h -> NEXT buffer (b16 write)
        #pragma unroll
        for (int mt = 0; mt < 2; mt++)
            #pragma unroll
            for (int rr = 0; rr < 4; rr++) {
                int nl = mt * 16 + nl0 + rr;       // local node (C/D row map)
                float eR; EXP2(eR, aR[mt][rr] + bR);
                float r = __builtin_amdgcn_rcpf(1.f + eR);
                float eZ; EXP2(eZ, aZ[mt][rr] + bZ);
                float z = __builtin_amdgcn_rcpf(1.f + eZ);
                float psc = aNX[mt][rr] + bXN + r * (aNH[mt][rr] + bHN);
                float ep; EXP2(ep, psc);
                float n = 1.f - 2.f * __builtin_amdgcn_rcpf(ep + 1.f);
                float h = n + z * (hprev[mt][rr] - n);
                hprev[mt][rr] = h;
                unsigned hw;
                asm("v_cvt_pk_bf16_f32 %0, %1, %2" : "=v"(hw) : "v"(h), "v"(0.f));
                int hb = (nl * 512 + 256 + 2 * j) ^ ((nl & 7) << 4);
                *(unsigned short*)(pN + hb) = (unsigned short)hw;
                if (nl < nvalid) {
                    qt[(mt * 16 + rr) * 256] = h;
                    if (t == TT - 1) qnb[(mt * 16 + rr) * 256] = h;
                }
            }
        // write staged x(t+1) into next buffer
        if (t < TT - 1) *(uint4*)(pN + sb) = uhi;
        qt += qstep;
    }
}

// ---------- GAT: fused matmul + att-dots; writes Hm in bf16 ----------
__global__ __launch_bounds__(256)
void gat_matmul(const float* __restrict__ G,
                const unsigned short* __restrict__ Wghi, const unsigned short* __restrict__ Wglo,
                const float* __restrict__ att_src, const float* __restrict__ att_dst,
                unsigned short* __restrict__ HmBf,
                float* __restrict__ a_src, float* __restrict__ a_dst, int N) {
    const int base = blockIdx.x * 32;
    const int tid  = threadIdx.x;
    const int lane = tid & 63;
    const int w    = tid >> 6;      // wave 0..3
    const int l15  = lane & 15;
    const int l4   = lane >> 4;

    __shared__ __align__(16) char smem[32768];   // hi @0, lo @16384
    __shared__ float sred1[4][32], sred2[4][32];

    const int snode = tid >> 3;
    const int sk    = (tid & 7) * 32;
    const int smask = (snode & 7) << 4;
    int node_s = base + snode; if (node_s >= N) node_s = N - 1;
    const float* gr = G + (size_t)node_s * 256 + sk;
    #pragma unroll
    for (int c = 0; c < 4; c++) {
        float4 v0 = *(const float4*)(gr + c * 8);
        float4 v1 = *(const float4*)(gr + c * 8 + 4);
        unsigned short h0 = f2bf(v0.x), h1 = f2bf(v0.y), h2 = f2bf(v0.z), h3 = f2bf(v0.w);
        unsigned short h4 = f2bf(v1.x), h5 = f2bf(v1.y), h6 = f2bf(v1.z), h7 = f2bf(v1.w);
        uint4 hi = {(unsigned)h0 | ((unsigned)h1 << 16), (unsigned)h2 | ((unsigned)h3 << 16),
                    (unsigned)h4 | ((unsigned)h5 << 16), (unsigned)h6 | ((unsigned)h7 << 16)};
        uint4 lo = {(unsigned)f2bf(v0.x - bf2f(h0)) | ((unsigned)f2bf(v0.y - bf2f(h1)) << 16),
                    (unsigned)f2bf(v0.z - bf2f(h2)) | ((unsigned)f2bf(v0.w - bf2f(h3)) << 16),
                    (unsigned)f2bf(v1.x - bf2f(h4)) | ((unsigned)f2bf(v1.y - bf2f(h5)) << 16),
                    (unsigned)f2bf(v1.z - bf2f(h6)) | ((unsigned)f2bf(v1.w - bf2f(h7)) << 16)};
        int addr = (snode * 512 + (sk + c * 8) * 2) ^ smask;
        *(uint4*)(smem + addr) = hi;
        *(uint4*)(smem + 16384 + addr) = lo;
    }
    __syncthreads();

    int aob[2], amask[2];
    #pragma unroll
    for (int mt = 0; mt < 2; mt++) {
        int row = mt * 16 + l15;
        aob[mt]   = row * 512 + l4 * 16;
        amask[mt] = (row & 7) << 4;
    }
    int bb[4];
    #pragma unroll
    for (int th = 0; th < 4; th++)
        bb[th] = (w * 64 + th * 16 + l15) * 256 + l4 * 8;

    f32x4 acc[4][2];
    #pragma unroll
    for (int th = 0; th < 4; th++)
        #pragma unroll
        for (int mt = 0; mt < 2; mt++) acc[th][mt] = (f32x4){0.f, 0.f, 0.f, 0.f};

    #pragma unroll
    for (int kc = 0; kc < 8; kc++) {
        short8 ah[2], al[2];
        #pragma unroll
        for (int mt = 0; mt < 2; mt++) {
            int ao = (aob[mt] + kc * 64) ^ amask[mt];
            ah[mt] = *(const short8*)(smem + ao);
            al[mt] = *(const short8*)(smem + 16384 + ao);
        }
        #pragma unroll
        for (int th = 0; th < 4; th++) {
            int bo = bb[th] + kc * 32;
            short8 bhf = *(const short8*)(Wghi + bo);
            short8 blf = *(const short8*)(Wglo + bo);
            #pragma unroll
            for (int mt = 0; mt < 2; mt++) {
                acc[th][mt] = __builtin_amdgcn_mfma_f32_16x16x32_bf16(ah[mt], bhf, acc[th][mt], 0, 0, 0);
                acc[th][mt] = __builtin_amdgcn_mfma_f32_16x16x32_bf16(al[mt], bhf, acc[th][mt], 0, 0, 0);
                acc[th][mt] = __builtin_amdgcn_mfma_f32_16x16x32_bf16(ah[mt], blf, acc[th][mt], 0, 0, 0);
            }
        }
    }

    // ---- epilogue: bf16 H write + fused attention dots ----
    float s1p[2][4], s2p[2][4];
    #pragma unroll
    for (int mt = 0; mt < 2; mt++)
        #pragma unroll
        for (int rr = 0; rr < 4; rr++) { s1p[mt][rr] = 0.f; s2p[mt][rr] = 0.f; }
    #pragma unroll
    for (int th = 0; th < 4; th++) {
        int col = w * 64 + th * 16 + l15;
        float as = att_src[col], ad = att_dst[col];
        #pragma unroll
        for (int mt = 0; mt < 2; mt++)
            #pragma unroll
            for (int rr = 0; rr < 4; rr++) {
                float v = acc[th][mt][rr];
                s1p[mt][rr] += v * as;
                s2p[mt][rr] += v * ad;
                int node = base + mt * 16 + l4 * 4 + rr;
                if (node < N) HmBf[(size_t)node * 256 + col] = f2bf(v);
            }
    }
    #pragma unroll
    for (int o = 1; o < 16; o <<= 1)
        #pragma unroll
        for (int mt = 0; mt < 2; mt++)
            #pragma unroll
            for (int rr = 0; rr < 4; rr++) {
                s1p[mt][rr] += __shfl_xor(s1p[mt][rr], o);
                s2p[mt][rr] += __shfl_xor(s2p[mt][rr], o);
            }
    if (l15 == 0) {
        #pragma unroll
        for (int mt = 0; mt < 2; mt++)
            #pragma unroll
            for (int rr = 0; rr < 4; rr++) {
                int nl = mt * 16 + l4 * 4 + rr;
                sred1[w][nl] = s1p[mt][rr];
                sred2[w][nl] = s2p[mt][rr];
            }
    }
    __syncthreads();
    if (tid < 32) {
        int node = base + tid;
        if (node < N) {
            a_src[node] = sred1[0][tid] + sred1[1][tid] + sred1[2][tid] + sred1[3][tid];
            a_dst[node] = sred2[0][tid] + sred2[1][tid] + sred2[2][tid] + sred2[3][tid];
        }
    }
}

// ---------- GAT: fused CSR aggregate — exp inline, denom in-wave ----------
__global__ void gat_aggregate(const unsigned short* __restrict__ HmBf,
                              const int* __restrict__ off,
                              const int* __restrict__ srcs_sorted,
                              const float* __restrict__ a_src, const float* __restrict__ a_dst,
                              const float* __restrict__ bias,
                              float* __restrict__ Gout, int N) {
    int n = blockIdx.x * 4 + (threadIdx.x >> 6);
    int lane = threadIdx.x & 63;
    if (n >= N) return;
    int s0 = off[n], s1 = off[n + 1];
    float ad = a_dst[n];
    float4 acc = {0.f, 0.f, 0.f, 0.f};
    float den = 0.f;
    int e = s0;
    for (; e + 4 <= s1; e += 4) {
        int sA = srcs_sorted[e],     sB = srcs_sorted[e + 1];
        int sC = srcs_sorted[e + 2], sD = srcs_sorted[e + 3];
        float vA = a_src[sA] + ad, vB = a_src[sB] + ad;
        float vC = a_src[sC] + ad, vD = a_src[sD] + ad;
        vA = vA > 0.f ? vA : 0.2f * vA;  float wA = __expf(vA);
        vB = vB > 0.f ? vB : 0.2f * vB;  float wB = __expf(vB);
        vC = vC > 0.f ? vC : 0.2f * vC;  float wC = __expf(vC);
        vD = vD > 0.f ? vD : 0.2f * vD;  float wD = __expf(vD);
        den += (wA + wB) + (wC + wD);
        ushort4 a = *(const ushort4*)(HmBf + (size_t)sA * 256 + lane * 4);
        ushort4 b = *(const ushort4*)(HmBf + (size_t)sB * 256 + lane * 4);
        ushort4 c = *(const ushort4*)(HmBf + (size_t)sC * 256 + lane * 4);
        ushort4 d = *(const ushort4*)(HmBf + (size_t)sD * 256 + lane * 4);
        acc.x += bf2f(a.x) * wA + bf2f(b.x) * wB + bf2f(c.x) * wC + bf2f(d.x) * wD;
        acc.y += bf2f(a.y) * wA + bf2f(b.y) * wB + bf2f(c.y) * wC + bf2f(d.y) * wD;
        acc.z += bf2f(a.z) * wA + bf2f(b.z) * wB + bf2f(c.z) * wC + bf2f(d.z) * wD;
        acc.w += bf2f(a.w) * wA + bf2f(b.w) * wB + bf2f(c.w) * wC + bf2f(d.w) * wD;
    }
    for (; e < s1; e++) {
        int s = srcs_sorted[e];
        float v = a_src[s] + ad;
        v = v > 0.f ? v : 0.2f * v;
        float wgt = __expf(v);
        den += wgt;
        ushort4 a = *(const ushort4*)(HmBf + (size_t)s * 256 + lane * 4);
        acc.x += bf2f(a.x) * wgt; acc.y += bf2f(a.y) * wgt;
        acc.z += bf2f(a.z) * wgt; acc.w += bf2f(a.w) * wgt;
    }
    float inv = (s1 > s0) ? 1.f / den : 0.f;
    float4 b4 = *(const float4*)(bias + lane * 4);
    float4 o = {acc.x * inv + b4.x, acc.y * inv + b4.y,
                acc.z * inv + b4.z, acc.w * inv + b4.w};
    *(float4*)(Gout + (size_t)n * 256 + lane * 4) = o;
}

// ---------- CSR build ----------
__global__ void zero_int(int* p, int n) {
    int i = blockIdx.x * 256 + threadIdx.x;
    if (i < n) p[i] = 0;
}
__global__ void deg_count(const int* __restrict__ dst, int* __restrict__ deg, int E) {
    int i = blockIdx.x * 256 + threadIdx.x;
    if (i < E) atomicAdd(deg + dst[i], 1);
}
__global__ void scan_k(const int* __restrict__ deg, int* __restrict__ off,
                       int* __restrict__ cursor, int n) {
    __shared__ int buf[256];
    __shared__ int carry_s;
    int tid = threadIdx.x;
    if (tid == 0) carry_s = 0;
    __syncthreads();
    for (int base = 0; base < n; base += 256) {
        int v = (base + tid < n) ? deg[base + tid] : 0;
        buf[tid] = v;
        __syncthreads();
        int x = v;
        for (int s = 1; s < 256; s <<= 1) {
            int tv = (tid >= s) ? buf[tid - s] : 0;
            __syncthreads();
            x += tv; buf[tid] = x;
            __syncthreads();
        }
        int carry = carry_s;
        if (base + tid < n) { off[base + tid] = carry + x - v; cursor[base + tid] = carry + x - v; }
        __syncthreads();
        if (tid == 255) carry_s = carry + x;
        __syncthreads();
    }
    if (tid == 0) off[n] = carry_s;
}
__global__ void scatter_k(const int* __restrict__ src, const int* __restrict__ dst,
                          int* __restrict__ cursor, int* __restrict__ srcs_sorted, int E) {
    int i = blockIdx.x * 256 + threadIdx.x;
    if (i >= E) return;
    int p = atomicAdd(cursor + dst[i], 1);
    srcs_sorted[p] = src[i];
}

// ---------- launch ----------
extern "C" void kernel_launch(void* const* d_in, const int* in_sizes, int n_in,
                              void* d_out, int out_size, void* d_ws, size_t ws_size,
                              hipStream_t stream) {
    const int N = in_sizes[0] / TT;
    const int E = in_sizes[1] / 2;
    const int EMBN = in_sizes[2];          // V * 128

    const int* X         = (const int*)d_in[0];
    const int* ei        = (const int*)d_in[1];
    const int* srcp      = ei;
    const int* dstp      = ei + E;
    const float* emb     = (const float*)d_in[2];
    const float* Wih_f   = (const float*)d_in[3];
    const float* Whh_f   = (const float*)d_in[4];
    const float* bih_f   = (const float*)d_in[5];
    const float* bhh_f   = (const float*)d_in[6];
    const float* Wih_b   = (const float*)d_in[7];
    const float* Whh_b   = (const float*)d_in[8];
    const float* bih_b   = (const float*)d_in[9];
    const float* bhh_b   = (const float*)d_in[10];
    const float* Wg      = (const float*)d_in[11];
    const float* att_src = (const float*)d_in[12];
    const float* att_dst = (const float*)d_in[13];
    const float* bg      = (const float*)d_in[14];

    float* out     = (float*)d_out;
    float* g_final = out;
    float* qn      = out + (size_t)N * 256;
    float* q       = out + (size_t)2 * N * 256;

    // ws layout
    float* w = (float*)d_ws;
    unsigned short* Whi_f = (unsigned short*)w; w += 49152;  // 384*256 ushort
    unsigned short* Whi_b = (unsigned short*)w; w += 49152;
    unsigned short* Wghi  = (unsigned short*)w; w += 32768;  // 256*256 ushort
    unsigned short* Wglo  = (unsigned short*)w; w += 32768;
    unsigned short* ehi   = (unsigned short*)w; w += (EMBN + 1) / 2;
    float* bufA  = w; w += (size_t)N * 256;
    float* bufB  = w; w += (size_t)N * 256;
    unsigned short* HmBf = (unsigned short*)w; w += (size_t)N * 128;  // N*256 ushorts
    float* a_src = w; w += N;
    float* a_dst = w; w += N;
    int* iw = (int*)w;
    int* deg         = iw; iw += N;
    int* cursor      = iw; iw += N;
    int* off         = iw; iw += N + 1;
    int* srcs_sorted = iw; iw += E;

    // 1. weight + emb plane prep
    prep_w<<<384, 256, 0, stream>>>(Wih_f, Whh_f, Wih_b, Whh_b, Wg,
                                    Whi_f, Whi_b, Wghi, Wglo);
    prep_emb<<<(EMBN + 255) / 256, 256, 0, stream>>>(emb, ehi, EMBN);
    // 2. fused biGRU, writes q and q_n
    dim3 ggrid((N + NB - 1) / NB, 2);
    gru_kernel<<<ggrid, 512, 0, stream>>>(X, ehi, Whi_f, Whi_b,
                                          bih_f, bhh_f, bih_b, bhh_b, q, qn, N);
    // 3. CSR build (once, reused by all 4 layers)
    zero_int<<<(N + 255) / 256, 256, 0, stream>>>(deg, N);
    deg_count<<<(E + 255) / 256, 256, 0, stream>>>(dstp, deg, E);
    scan_k<<<1, 256, 0, stream>>>(deg, off, cursor, N);
    scatter_k<<<(E + 255) / 256, 256, 0, stream>>>(srcp, dstp, cursor, srcs_sorted, E);
    // 4. 4 GAT layers (shared weights); 2 kernels/layer
    const float* gin = qn;
    float* gouts[4] = {bufA, bufB, bufA, g_final};
    for (int l = 0; l < 4; l++) {
        gat_matmul<<<(N + 31) / 32, 256, 0, stream>>>(gin, Wghi, Wglo, att_src, att_dst,
                                                      HmBf, a_src, a_dst, N);
        gat_aggregate<<<(N + 3) / 4, 256, 0, stream>>>(HmBf, off, srcs_sorted,
                                                       a_src, a_dst, bg, gouts[l], N);
        gin = gouts[l];
    }
}